// Round 1
// baseline (3107.278 us; speedup 1.0000x reference)
//
#include <hip/hip_runtime.h>

#define T_STEPS 25
#define BATCH   4096
#define DIN     784
#define DH      1000
#define HP      1024   // padded hidden dim
#define DOUT    10

// GEMM tile params
#define BM   128
#define BN   64
#define BK   16
#define APAD 4
#define BPAD 4

// ---------------------------------------------------------------------------
// Prep: zero-padded copies of w1 (HPxDIN), b1 (HP), w2 (DOUTxHP).
// ---------------------------------------------------------------------------
__global__ void prep_kernel(const float* __restrict__ w1, const float* __restrict__ b1,
                            const float* __restrict__ w2,
                            float* __restrict__ w1p, float* __restrict__ b1p,
                            float* __restrict__ w2p)
{
    int idx = blockIdx.x * blockDim.x + threadIdx.x;
    int stride = gridDim.x * blockDim.x;
    for (int i = idx; i < HP * DIN; i += stride)
        w1p[i] = (i < DH * DIN) ? w1[i] : 0.f;   // rows contiguous: first DH rows copy, rest zero
    for (int i = idx; i < HP; i += stride)
        b1p[i] = (i < DH) ? b1[i] : 0.f;
    for (int i = idx; i < DOUT * HP; i += stride) {
        int o = i >> 10, h = i & (HP - 1);
        w2p[i] = (h < DH) ? w2[o * DH + h] : 0.f;
    }
}

// ---------------------------------------------------------------------------
// Layer-1 GEMM (C = x_t @ w1p^T + b1p) with fused LIF update.
// 128x64 block tile, 256 threads (4 waves), 8x4 per-thread tile, BK=16.
// Fully divisible: 4096/128=32, 1024/64=16, 784/16=49.
// ---------------------------------------------------------------------------
__global__ __launch_bounds__(256, 2)
void gemm1_step_kernel(const float* __restrict__ X,   // [BATCH][DIN] (slice at t)
                       const float* __restrict__ W,   // w1p [HP][DIN]
                       const float* __restrict__ Bv,  // b1p [HP]
                       float* __restrict__ mem1,      // [BATCH][HP]
                       float* __restrict__ spk1)      // [BATCH][HP]
{
    __shared__ float As[BK][BM + APAD];
    __shared__ float Bs[BK][BN + BPAD];

    const int tid = threadIdx.x;
    const int rowBase = blockIdx.y * BM;
    const int colBase = blockIdx.x * BN;

    const int wave = tid >> 6;
    const int lane = tid & 63;
    const int wm = wave >> 1;          // 0..1 : 64-row subtile
    const int wn = wave & 1;           // 0..1 : 32-col subtile
    const int ty = lane >> 3;          // 0..7 : 8 rows each
    const int tx = lane & 7;           // 0..7 : 4 cols each
    const int fragRow = wm * 64 + ty * 8;
    const int fragCol = wn * 32 + tx * 4;

    float acc[8][4];
    #pragma unroll
    for (int i = 0; i < 8; ++i)
        #pragma unroll
        for (int j = 0; j < 4; ++j) acc[i][j] = 0.f;

    for (int k0 = 0; k0 < DIN; k0 += BK) {
        // stage A tile: 128 rows x 16 k  (512 float4 chunks / 256 threads = 2 each)
        #pragma unroll
        for (int r = 0; r < 2; ++r) {
            int c = tid + r * 256;
            int m = c >> 2;
            int kc = (c & 3) << 2;
            float4 v = *(const float4*)(X + (size_t)(rowBase + m) * DIN + k0 + kc);
            As[kc + 0][m] = v.x;
            As[kc + 1][m] = v.y;
            As[kc + 2][m] = v.z;
            As[kc + 3][m] = v.w;
        }
        // stage B tile: 64 rows x 16 k  (256 chunks / 256 threads = 1 each)
        {
            int n = tid >> 2;
            int kc = (tid & 3) << 2;
            float4 v = *(const float4*)(W + (size_t)(colBase + n) * DIN + k0 + kc);
            Bs[kc + 0][n] = v.x;
            Bs[kc + 1][n] = v.y;
            Bs[kc + 2][n] = v.z;
            Bs[kc + 3][n] = v.w;
        }
        __syncthreads();

        #pragma unroll
        for (int k = 0; k < BK; ++k) {
            float a[8], b[4];
            *(float4*)&a[0] = *(const float4*)&As[k][fragRow];
            *(float4*)&a[4] = *(const float4*)&As[k][fragRow + 4];
            *(float4*)&b[0] = *(const float4*)&Bs[k][fragCol];
            #pragma unroll
            for (int i = 0; i < 8; ++i)
                #pragma unroll
                for (int j = 0; j < 4; ++j)
                    acc[i][j] = fmaf(a[i], b[j], acc[i][j]);
        }
        __syncthreads();
    }

    // Fused LIF epilogue: reset from OLD mem, spike from NEW mem.
    const float4 bb = *(const float4*)(Bv + colBase + fragCol);
    const float bv[4] = {bb.x, bb.y, bb.z, bb.w};
    #pragma unroll
    for (int i = 0; i < 8; ++i) {
        size_t idx = (size_t)(rowBase + fragRow + i) * HP + colBase + fragCol;
        float4 mo = *(const float4*)(mem1 + idx);
        float mold[4] = {mo.x, mo.y, mo.z, mo.w};
        float4 mn4, sp4;
        float* mn = &mn4.x;
        float* sp = &sp4.x;
        #pragma unroll
        for (int j = 0; j < 4; ++j) {
            float cur = acc[i][j] + bv[j];
            float r = (mold[j] > 1.0f) ? 1.0f : 0.0f;
            float v = 0.95f * mold[j] + cur - r;   // beta*mem + cur - reset*THR
            mn[j] = v;
            sp[j] = (v > 1.0f) ? 1.0f : 0.0f;
        }
        *(float4*)(mem1 + idx) = mn4;
        *(float4*)(spk1 + idx) = sp4;
    }
}

// ---------------------------------------------------------------------------
// Layer 2: cur2 = spk1 @ w2p^T + b2, LIF update of mem2, emit spk2 (+ final mem2).
// One block per batch row; 256 threads reduce over HP=1024.
// ---------------------------------------------------------------------------
__global__ __launch_bounds__(256)
void layer2_step_kernel(const float* __restrict__ spk1, const float* __restrict__ w2p,
                        const float* __restrict__ b2, float* __restrict__ mem2,
                        float* __restrict__ out, int t)
{
    const int b = blockIdx.x;
    const int tid = threadIdx.x;
    const float* srow = spk1 + (size_t)b * HP;

    float acc[DOUT];
    #pragma unroll
    for (int o = 0; o < DOUT; ++o) acc[o] = 0.f;

    #pragma unroll
    for (int i = 0; i < HP / 256; ++i) {
        int h = tid + i * 256;
        float s = srow[h];
        #pragma unroll
        for (int o = 0; o < DOUT; ++o)
            acc[o] = fmaf(s, w2p[o * HP + h], acc[o]);
    }

    // wave reduce (64-lane)
    #pragma unroll
    for (int o = 0; o < DOUT; ++o) {
        float v = acc[o];
        #pragma unroll
        for (int off = 32; off > 0; off >>= 1) v += __shfl_down(v, off, 64);
        acc[o] = v;
    }

    __shared__ float red[4][DOUT];
    const int lane = tid & 63, wave = tid >> 6;
    if (lane == 0) {
        #pragma unroll
        for (int o = 0; o < DOUT; ++o) red[wave][o] = acc[o];
    }
    __syncthreads();

    if (tid < DOUT) {
        float cur = red[0][tid] + red[1][tid] + red[2][tid] + red[3][tid] + b2[tid];
        float m = mem2[b * DOUT + tid];
        float r = (m > 1.0f) ? 1.0f : 0.0f;
        float mn = 0.95f * m + cur - r;
        mem2[b * DOUT + tid] = mn;
        out[(size_t)t * (BATCH * DOUT) + b * DOUT + tid] = (mn > 1.0f) ? 1.0f : 0.0f;
        if (t == T_STEPS - 1)
            out[(size_t)T_STEPS * BATCH * DOUT + b * DOUT + tid] = mn;
    }
}

// ---------------------------------------------------------------------------
extern "C" void kernel_launch(void* const* d_in, const int* in_sizes, int n_in,
                              void* d_out, int out_size, void* d_ws, size_t ws_size,
                              hipStream_t stream)
{
    const float* x  = (const float*)d_in[0];
    const float* w1 = (const float*)d_in[1];
    const float* b1 = (const float*)d_in[2];
    const float* w2 = (const float*)d_in[3];
    const float* b2 = (const float*)d_in[4];
    float* out = (float*)d_out;
    float* ws  = (float*)d_ws;

    // ws layout (floats). Total ~9.25M floats ~= 35.3 MB.
    float* w1p  = ws;                               // HP*DIN
    float* b1p  = w1p + HP * DIN;                   // HP
    float* w2p  = b1p + HP;                         // DOUT*HP
    float* mem1 = w2p + DOUT * HP;                  // BATCH*HP
    float* mem2 = mem1 + (size_t)BATCH * HP;        // BATCH*DOUT (contiguous with mem1)
    float* spk1 = mem2 + BATCH * DOUT;              // BATCH*HP

    // zero the recurrent state every call (deterministic)
    hipMemsetAsync(mem1, 0, ((size_t)BATCH * HP + BATCH * DOUT) * sizeof(float), stream);

    prep_kernel<<<1024, 256, 0, stream>>>(w1, b1, w2, w1p, b1p, w2p);

    dim3 grid(HP / BN, BATCH / BM);   // 16 x 32 = 512 blocks
    for (int t = 0; t < T_STEPS; ++t) {
        gemm1_step_kernel<<<grid, 256, 0, stream>>>(
            x + (size_t)t * BATCH * DIN, w1p, b1p, mem1, spk1);
        layer2_step_kernel<<<BATCH, 256, 0, stream>>>(
            spk1, w2p, b2, mem2, out, t);
    }
}

// Round 2
// 887.042 us; speedup vs baseline: 3.5030x; 3.5030x over previous
//
#include <hip/hip_runtime.h>

typedef _Float16 f16;
typedef _Float16 f16x4 __attribute__((ext_vector_type(4)));
typedef _Float16 f16x8 __attribute__((ext_vector_type(8)));
typedef float f32x4 __attribute__((ext_vector_type(4)));

#define T_STEPS 25
#define BATCH   4096
#define DIN     784
#define DH      1000
#define HP      1024
#define DOUT    10
#define MROWS   (T_STEPS * BATCH)   // 102400
#define KSEG    800                 // 784 padded to 800 (25 * 32)
#define KA      (2 * KSEG)          // A width: [xhi | xlo] = 1600
#define KB      (3 * KSEG)          // B width: [whi | whi | wlo] = 2400
#define BM      128
#define BN      128
#define BK      32

#define GLOAD_LDS16(gptr, lptr) \
    __builtin_amdgcn_global_load_lds( \
        (const __attribute__((address_space(1))) void*)(gptr), \
        (__attribute__((address_space(3))) void*)(lptr), 16, 0, 0)

// ---------------------------------------------------------------------------
// Convert X (fp32 [MROWS][784]) -> Ah f16 [MROWS][1600] = [hi(800) | lo(800)],
// zero-padded cols 784..799 of each segment.
// ---------------------------------------------------------------------------
__global__ void aconv_kernel(const float* __restrict__ x, f16* __restrict__ Ah)
{
    const int total = MROWS * 200;  // 200 chunks of 4 cols per row
    for (int idx = blockIdx.x * blockDim.x + threadIdx.x; idx < total;
         idx += gridDim.x * blockDim.x) {
        const int r  = idx / 200;
        const int c4 = (idx - r * 200) * 4;
        f16x4 hi, lo;
        if (c4 < DIN) {
            const float4 v = *(const float4*)(x + (size_t)r * DIN + c4);
            const float vv[4] = {v.x, v.y, v.z, v.w};
            #pragma unroll
            for (int j = 0; j < 4; ++j) {
                f16 h = (f16)vv[j];
                hi[j] = h;
                lo[j] = (f16)(vv[j] - (float)h);
            }
        } else {
            #pragma unroll
            for (int j = 0; j < 4; ++j) { hi[j] = (f16)0.f; lo[j] = (f16)0.f; }
        }
        *(f16x4*)(Ah + (size_t)r * KA + c4)        = hi;
        *(f16x4*)(Ah + (size_t)r * KA + KSEG + c4) = lo;
    }
}

// ---------------------------------------------------------------------------
// Convert weights: Wh f16 [HP][2400] = [whi | whi | wlo] (row pad 1000->1024,
// col pad 784->800 per segment); b1p fp32 [HP]; w2t fp32 [HP][10] transposed.
// ---------------------------------------------------------------------------
__global__ void wconv_kernel(const float* __restrict__ w1, const float* __restrict__ b1,
                             const float* __restrict__ w2,
                             f16* __restrict__ Wh, float* __restrict__ b1p,
                             float* __restrict__ w2t)
{
    const int stride = gridDim.x * blockDim.x;
    const int tid0 = blockIdx.x * blockDim.x + threadIdx.x;
    for (int idx = tid0; idx < HP * KB; idx += stride) {
        const int n  = idx / KB;
        const int k  = idx - n * KB;
        const int seg = k / KSEG;
        const int kc  = k - seg * KSEG;
        float w = (n < DH && kc < DIN) ? w1[n * DIN + kc] : 0.f;
        f16 h = (f16)w;
        Wh[idx] = (seg < 2) ? h : (f16)(w - (float)h);
    }
    for (int idx = tid0; idx < HP; idx += stride)
        b1p[idx] = (idx < DH) ? b1[idx] : 0.f;
    for (int idx = tid0; idx < HP * DOUT; idx += stride) {
        const int h = idx / DOUT;
        const int o = idx - h * DOUT;
        w2t[idx] = (h < DH) ? w2[o * DH + h] : 0.f;
    }
}

// ---------------------------------------------------------------------------
// cur1 = Ah @ Wh^T + b1p   (f16 split-2, 3 cross terms, fp32 accumulate)
// m97 structure: 128x128 tile, 256 thr (4 waves 2x2), BK=32, global_load_lds,
// mfma_f32_16x16x32_f16, XCD-swizzled blockIdx.
// Grid: (MROWS/128) * (HP/128) = 800 * 8 = 6400 blocks.
// ---------------------------------------------------------------------------
__global__ __launch_bounds__(256, 2)
void gemm_kernel(const f16* __restrict__ A, const f16* __restrict__ B,
                 const float* __restrict__ bias, float* __restrict__ C)
{
    __shared__ f16 As[BM * BK];   // [m][k], 64B rows
    __shared__ f16 Bs[BN * BK];   // [n][k]

    const int bid = blockIdx.x;
    const int swz = (bid & 7) * 800 + (bid >> 3);   // bijective: 6400 % 8 == 0
    const int mt = swz >> 3;
    const int nt = swz & 7;
    const int rowBase = mt * BM;
    const int colBase = nt * BN;

    const int tid  = threadIdx.x;
    const int wave = tid >> 6;
    const int lane = tid & 63;
    const int wm = wave >> 1, wn = wave & 1;

    // staging: thread covers (row = tid/4, 8-f16 chunk = tid%4) per 64-row half
    const int srow = tid >> 2;
    const int scol = (tid & 3) * 8;
    const f16* Ag0 = A + (size_t)(rowBase + srow) * KA + scol;
    const f16* Ag1 = Ag0 + (size_t)64 * KA;
    const f16* Bg0 = B + (size_t)(colBase + srow) * KB + scol;
    const f16* Bg1 = Bg0 + (size_t)64 * KB;
    f16* Al0 = As + (wave * 16) * BK;          // wave-uniform LDS bases
    f16* Al1 = As + (64 + wave * 16) * BK;
    f16* Bl0 = Bs + (wave * 16) * BK;
    f16* Bl1 = Bs + (64 + wave * 16) * BK;

    f32x4 acc[4][4];
    #pragma unroll
    for (int m = 0; m < 4; ++m)
        #pragma unroll
        for (int n = 0; n < 4; ++n)
            acc[m][n] = (f32x4){0.f, 0.f, 0.f, 0.f};

    const int arow = wm * 64 + (lane & 15);
    const int brow = wn * 64 + (lane & 15);
    const int kg   = (lane >> 4) * 8;

    for (int kk = 0; kk < KB; kk += BK) {
        const int ak = (kk < KA) ? kk : (kk - KA);   // third segment re-reads xhi
        GLOAD_LDS16(Ag0 + ak, Al0);
        GLOAD_LDS16(Ag1 + ak, Al1);
        GLOAD_LDS16(Bg0 + kk, Bl0);
        GLOAD_LDS16(Bg1 + kk, Bl1);
        __syncthreads();   // compiler drains vmcnt before s_barrier

        f16x8 af[4], bf[4];
        #pragma unroll
        for (int m = 0; m < 4; ++m)
            af[m] = *(const f16x8*)&As[(arow + m * 16) * BK + kg];
        #pragma unroll
        for (int n = 0; n < 4; ++n)
            bf[n] = *(const f16x8*)&Bs[(brow + n * 16) * BK + kg];
        #pragma unroll
        for (int m = 0; m < 4; ++m)
            #pragma unroll
            for (int n = 0; n < 4; ++n)
                acc[m][n] = __builtin_amdgcn_mfma_f32_16x16x32_f16(
                    af[m], bf[n], acc[m][n], 0, 0, 0);
        __syncthreads();
    }

    // epilogue: C/D layout col = lane&15, row = (lane>>4)*4 + reg  [m89]
    const int c_col0 = colBase + wn * 64 + (lane & 15);
    const int c_row0 = rowBase + wm * 64 + (lane >> 4) * 4;
    #pragma unroll
    for (int n = 0; n < 4; ++n) {
        const int gcol = c_col0 + n * 16;
        const float bv = bias[gcol];
        #pragma unroll
        for (int m = 0; m < 4; ++m) {
            const int grow = c_row0 + m * 16;
            #pragma unroll
            for (int r = 0; r < 4; ++r)
                C[(size_t)(grow + r) * HP + gcol] = acc[m][n][r] + bv;
        }
    }
}

// ---------------------------------------------------------------------------
// Temporal phase: per batch row, all 25 steps with mem1 (16 f32/lane) and
// mem2 (lane-replicated 10 f32) in registers. 4 waves/block, 1 row/wave.
// w2 staged in LDS [1024][10] (stride 10 -> 2-way bank alias = free).
// ---------------------------------------------------------------------------
__global__ __launch_bounds__(256)
void phase2_kernel(const float* __restrict__ cur1, const float* __restrict__ w2t,
                   const float* __restrict__ b2, float* __restrict__ out)
{
    __shared__ float w2s[HP * DOUT];   // 40 KB
    const int tid = threadIdx.x;
    for (int i = tid; i < HP * DOUT; i += 256) w2s[i] = w2t[i];

    const int lane = tid & 63;
    const int wave = tid >> 6;
    const int b = blockIdx.x * 4 + wave;

    float m1[16];   // h = c*256 + lane*4 + j
    #pragma unroll
    for (int i = 0; i < 16; ++i) m1[i] = 0.f;
    float m2[DOUT], b2r[DOUT];
    #pragma unroll
    for (int o = 0; o < DOUT; ++o) { m2[o] = 0.f; b2r[o] = b2[o]; }
    __syncthreads();

    for (int t = 0; t < T_STEPS; ++t) {
        const float* cr = cur1 + ((size_t)t * BATCH + b) * HP;
        float p[DOUT];
        #pragma unroll
        for (int o = 0; o < DOUT; ++o) p[o] = 0.f;

        #pragma unroll
        for (int c = 0; c < 4; ++c) {
            const float4 cu = *(const float4*)(cr + c * 256 + lane * 4);
            const float cv[4] = {cu.x, cu.y, cu.z, cu.w};
            #pragma unroll
            for (int j = 0; j < 4; ++j) {
                const float mo = m1[c * 4 + j];
                const float rs = (mo > 1.0f) ? 1.0f : 0.0f;
                const float mn = 0.95f * mo + cv[j] - rs;   // reset-by-subtraction
                m1[c * 4 + j] = mn;
                if (mn > 1.0f) {   // spike: add w2 row (spk is exactly 1.0)
                    const float* wr = w2s + (c * 256 + lane * 4 + j) * DOUT;
                    #pragma unroll
                    for (int o = 0; o < DOUT; ++o) p[o] += wr[o];
                }
            }
        }
        // wave-wide butterfly reduce: every lane ends with the full sum
        #pragma unroll
        for (int o = 0; o < DOUT; ++o) {
            float v = p[o];
            #pragma unroll
            for (int msk = 32; msk > 0; msk >>= 1) v += __shfl_xor(v, msk, 64);
            p[o] = v;
        }
        // LIF-2 (replicated on all lanes; identical arithmetic -> identical state)
        #pragma unroll
        for (int o = 0; o < DOUT; ++o) {
            const float cur2 = p[o] + b2r[o];
            const float mo = m2[o];
            const float rs = (mo > 1.0f) ? 1.0f : 0.0f;
            m2[o] = 0.95f * mo + cur2 - rs;
        }
        if (lane < DOUT)
            out[(size_t)t * (BATCH * DOUT) + (size_t)b * DOUT + lane] =
                (m2[lane] > 1.0f) ? 1.0f : 0.0f;
    }
    if (lane < DOUT)
        out[(size_t)T_STEPS * BATCH * DOUT + (size_t)b * DOUT + lane] = m2[lane];
}

// ---------------------------------------------------------------------------
extern "C" void kernel_launch(void* const* d_in, const int* in_sizes, int n_in,
                              void* d_out, int out_size, void* d_ws, size_t ws_size,
                              hipStream_t stream)
{
    const float* x  = (const float*)d_in[0];
    const float* w1 = (const float*)d_in[1];
    const float* b1 = (const float*)d_in[2];
    const float* w2 = (const float*)d_in[3];
    const float* b2 = (const float*)d_in[4];
    float* out = (float*)d_out;

    // ws layout (bytes):
    char* wsb = (char*)d_ws;
    f16*   Ah   = (f16*)(wsb);                                   // 327,680,000
    f16*   Wh   = (f16*)(wsb + 327680000);                       //   4,915,200
    float* cur1 = (float*)(wsb + 327680000 + 4915200);           // 419,430,400
    float* b1p  = (float*)(wsb + 327680000 + 4915200 + 419430400);           // 4,096
    float* w2t  = (float*)(wsb + 327680000 + 4915200 + 419430400 + 4096);    // 40,960
    // total ~752.1 MB

    aconv_kernel<<<4096, 256, 0, stream>>>(x, Ah);
    wconv_kernel<<<1024, 256, 0, stream>>>(w1, b1, w2, Wh, b1p, w2t);
    gemm_kernel<<<6400, 256, 0, stream>>>(Ah, Wh, b1p, cur1);
    phase2_kernel<<<1024, 256, 0, stream>>>(cur1, w2t, b2, out);
}

// Round 3
// 764.179 us; speedup vs baseline: 4.0662x; 1.1608x over previous
//
#include <hip/hip_runtime.h>

typedef _Float16 f16;
typedef _Float16 f16x4 __attribute__((ext_vector_type(4)));
typedef _Float16 f16x8 __attribute__((ext_vector_type(8)));
typedef float f32x4 __attribute__((ext_vector_type(4)));

#define T_STEPS 25
#define BATCH   4096
#define DIN     784
#define DH      1000
#define HP      1024
#define DOUT    10
#define MROWS   (T_STEPS * BATCH)   // 102400
#define KSEG    800                 // 784 padded to 800 (25 * 32)
#define KA      (2 * KSEG)          // A width: [xhi | xlo] = 1600
#define KB      (3 * KSEG)          // B width: [whi | whi | wlo] = 2400
#define NTILES  (KB / 32)           // 75 K-tiles of 32

// ---------------------------------------------------------------------------
// Convert X (fp32 [MROWS][784]) -> Ah f16 [MROWS][1600] = [hi(800) | lo(800)]
// ---------------------------------------------------------------------------
__global__ void aconv_kernel(const float* __restrict__ x, f16* __restrict__ Ah)
{
    const int total = MROWS * 200;
    for (int idx = blockIdx.x * blockDim.x + threadIdx.x; idx < total;
         idx += gridDim.x * blockDim.x) {
        const int r  = idx / 200;
        const int c4 = (idx - r * 200) * 4;
        f16x4 hi, lo;
        if (c4 < DIN) {
            const float4 v = *(const float4*)(x + (size_t)r * DIN + c4);
            const float vv[4] = {v.x, v.y, v.z, v.w};
            #pragma unroll
            for (int j = 0; j < 4; ++j) {
                f16 h = (f16)vv[j];
                hi[j] = h;
                lo[j] = (f16)(vv[j] - (float)h);
            }
        } else {
            #pragma unroll
            for (int j = 0; j < 4; ++j) { hi[j] = (f16)0.f; lo[j] = (f16)0.f; }
        }
        *(f16x4*)(Ah + (size_t)r * KA + c4)        = hi;
        *(f16x4*)(Ah + (size_t)r * KA + KSEG + c4) = lo;
    }
}

// ---------------------------------------------------------------------------
// Weights: Wh f16 [HP][2400] = [whi | whi | wlo]; b1p fp32; w2t fp32 [HP][10].
// ---------------------------------------------------------------------------
__global__ void wconv_kernel(const float* __restrict__ w1, const float* __restrict__ b1,
                             const float* __restrict__ w2,
                             f16* __restrict__ Wh, float* __restrict__ b1p,
                             float* __restrict__ w2t)
{
    const int stride = gridDim.x * blockDim.x;
    const int tid0 = blockIdx.x * blockDim.x + threadIdx.x;
    for (int idx = tid0; idx < HP * KB; idx += stride) {
        const int n  = idx / KB;
        const int k  = idx - n * KB;
        const int seg = k / KSEG;
        const int kc  = k - seg * KSEG;
        float w = (n < DH && kc < DIN) ? w1[n * DIN + kc] : 0.f;
        f16 h = (f16)w;
        Wh[idx] = (seg < 2) ? h : (f16)(w - (float)h);
    }
    for (int idx = tid0; idx < HP; idx += stride)
        b1p[idx] = (idx < DH) ? b1[idx] : 0.f;
    for (int idx = tid0; idx < HP * DOUT; idx += stride) {
        const int h = idx / DOUT;
        const int o = idx - h * DOUT;
        w2t[idx] = (h < DH) ? w2[o * DH + h] : 0.f;
    }
}

// ---------------------------------------------------------------------------
// 256x256-tile deep-pipelined GEMM: cur1 = Ah @ Wh^T + b1p.
// 512 thr (8 waves 2Mx4N), BK=32, 4-deep LDS ring (128 KB), counted vmcnt(8),
// raw s_barrier + lgkmcnt(0) + sched_barrier, setprio around MFMA, XOR swizzle
// both-sides (pre-swizzled global src for linear global_load_lds + swz ds_read).
// Grid: (MROWS/256) * (HP/256) = 400 * 4 = 1600 blocks (1600 % 8 == 0).
// ---------------------------------------------------------------------------
#define GL(gp, ldsoff) __builtin_amdgcn_global_load_lds( \
    (const __attribute__((address_space(1))) void*)(gp), \
    (__attribute__((address_space(3))) void*)(lds + (ldsoff)), 16, 0, 0)

// A-tile staging for K-tile tt into ring slot tt&3 (2 x global_load_lds)
#define STAGE_A(tt) do { \
    const int ak_ = (((tt) < 50) ? (tt) : ((tt) - 50)) * 32; \
    GL(Ag + ak_,            ((tt) & 3) * 8192 + widoff); \
    GL(Ag + ak_ + 128 * KA, ((tt) & 3) * 8192 + 4096 + widoff); } while (0)
// B-tile staging
#define STAGE_B(tt) do { \
    const int bk_ = (tt) * 32; \
    GL(Bg + bk_,                     32768 + ((tt) & 3) * 8192 + widoff); \
    GL(Bg + bk_ + (size_t)128 * KB,  32768 + ((tt) & 3) * 8192 + 4096 + widoff); } while (0)

#define MFMA16(M0) \
    acc[M0+0][0] = __builtin_amdgcn_mfma_f32_16x16x32_f16(af0, bf0, acc[M0+0][0], 0, 0, 0); \
    acc[M0+0][1] = __builtin_amdgcn_mfma_f32_16x16x32_f16(af0, bf1, acc[M0+0][1], 0, 0, 0); \
    acc[M0+0][2] = __builtin_amdgcn_mfma_f32_16x16x32_f16(af0, bf2, acc[M0+0][2], 0, 0, 0); \
    acc[M0+0][3] = __builtin_amdgcn_mfma_f32_16x16x32_f16(af0, bf3, acc[M0+0][3], 0, 0, 0); \
    acc[M0+1][0] = __builtin_amdgcn_mfma_f32_16x16x32_f16(af1, bf0, acc[M0+1][0], 0, 0, 0); \
    acc[M0+1][1] = __builtin_amdgcn_mfma_f32_16x16x32_f16(af1, bf1, acc[M0+1][1], 0, 0, 0); \
    acc[M0+1][2] = __builtin_amdgcn_mfma_f32_16x16x32_f16(af1, bf2, acc[M0+1][2], 0, 0, 0); \
    acc[M0+1][3] = __builtin_amdgcn_mfma_f32_16x16x32_f16(af1, bf3, acc[M0+1][3], 0, 0, 0); \
    acc[M0+2][0] = __builtin_amdgcn_mfma_f32_16x16x32_f16(af2, bf0, acc[M0+2][0], 0, 0, 0); \
    acc[M0+2][1] = __builtin_amdgcn_mfma_f32_16x16x32_f16(af2, bf1, acc[M0+2][1], 0, 0, 0); \
    acc[M0+2][2] = __builtin_amdgcn_mfma_f32_16x16x32_f16(af2, bf2, acc[M0+2][2], 0, 0, 0); \
    acc[M0+2][3] = __builtin_amdgcn_mfma_f32_16x16x32_f16(af2, bf3, acc[M0+2][3], 0, 0, 0); \
    acc[M0+3][0] = __builtin_amdgcn_mfma_f32_16x16x32_f16(af3, bf0, acc[M0+3][0], 0, 0, 0); \
    acc[M0+3][1] = __builtin_amdgcn_mfma_f32_16x16x32_f16(af3, bf1, acc[M0+3][1], 0, 0, 0); \
    acc[M0+3][2] = __builtin_amdgcn_mfma_f32_16x16x32_f16(af3, bf2, acc[M0+3][2], 0, 0, 0); \
    acc[M0+3][3] = __builtin_amdgcn_mfma_f32_16x16x32_f16(af3, bf3, acc[M0+3][3], 0, 0, 0);

// One K-tile = 2 phases. STG: stage tile tt+3. WAITSTR: vmcnt wait in phase 2.
#define BODY(tt, STG, WAITSTR) do { \
    const int bA = ((tt) & 3) * 8192; \
    const int bB = 32768 + ((tt) & 3) * 8192; \
    f16x8 af0, af1, af2, af3, bf0, bf1, bf2, bf3; \
    /* phase 1: m-half 0 */ \
    af0 = *(const f16x8*)(lds + bA + aoffb + 0 * 512); \
    af1 = *(const f16x8*)(lds + bA + aoffb + 1 * 512); \
    af2 = *(const f16x8*)(lds + bA + aoffb + 2 * 512); \
    af3 = *(const f16x8*)(lds + bA + aoffb + 3 * 512); \
    bf0 = *(const f16x8*)(lds + bB + boffb + 0 * 512); \
    bf1 = *(const f16x8*)(lds + bB + boffb + 1 * 512); \
    bf2 = *(const f16x8*)(lds + bB + boffb + 2 * 512); \
    bf3 = *(const f16x8*)(lds + bB + boffb + 3 * 512); \
    if (STG) STAGE_A((tt) + 3); \
    __builtin_amdgcn_s_barrier(); \
    asm volatile("s_waitcnt lgkmcnt(0)" ::: "memory"); \
    __builtin_amdgcn_sched_barrier(0); \
    __builtin_amdgcn_s_setprio(1); \
    MFMA16(0) \
    __builtin_amdgcn_s_setprio(0); \
    __builtin_amdgcn_s_barrier(); \
    /* phase 2: m-half 1 (bf held in regs) */ \
    af0 = *(const f16x8*)(lds + bA + aoffb + 4 * 512); \
    af1 = *(const f16x8*)(lds + bA + aoffb + 5 * 512); \
    af2 = *(const f16x8*)(lds + bA + aoffb + 6 * 512); \
    af3 = *(const f16x8*)(lds + bA + aoffb + 7 * 512); \
    if (STG) STAGE_B((tt) + 3); \
    asm volatile(WAITSTR ::: "memory"); \
    __builtin_amdgcn_s_barrier(); \
    asm volatile("s_waitcnt lgkmcnt(0)" ::: "memory"); \
    __builtin_amdgcn_sched_barrier(0); \
    __builtin_amdgcn_s_setprio(1); \
    MFMA16(4) \
    __builtin_amdgcn_s_setprio(0); \
    __builtin_amdgcn_s_barrier(); \
} while (0)

__global__ __launch_bounds__(512, 2)
void gemm_kernel(const f16* __restrict__ A, const f16* __restrict__ B,
                 const float* __restrict__ bias, float* __restrict__ C)
{
    __shared__ f16 lds[65536];   // 128 KB: A ring [4][8192] | B ring at +32768

    const int bid = blockIdx.x;
    const int swz = (bid & 7) * 200 + (bid >> 3);   // bijective XCD chunking
    const int mt = swz >> 2;
    const int nt = swz & 3;
    const size_t rowBase = (size_t)mt * 256;
    const int colBase = nt * 256;

    const int tid  = threadIdx.x;
    const int wid  = tid >> 6;
    const int lane = tid & 63;
    const int wm = wid >> 2;      // 0..1
    const int wn = wid & 3;       // 0..3

    // staging source (pre-swizzled global chunk: g = chunk ^ ((row>>1)&3))
    const int srow = tid >> 2;
    const int g = (tid & 3) ^ ((tid >> 3) & 3);
    const f16* Ag = A + (rowBase + srow) * KA + g * 8;
    const f16* Bg = B + (size_t)(colBase + srow) * KB + g * 8;
    const int widoff = wid * 512;   // f16 elems: wave-uniform LDS base (1 KB/wave)

    // ds_read addressing (swizzled chunk, same XOR both sides)
    const int cq = (lane >> 4) ^ (((lane & 15) >> 1) & 3);
    const int aoffb = (wm * 128 + (lane & 15)) * 32 + cq * 8;
    const int boffb = (wn * 64  + (lane & 15)) * 32 + cq * 8;

    f32x4 acc[8][4];
    #pragma unroll
    for (int m = 0; m < 8; ++m)
        #pragma unroll
        for (int n = 0; n < 4; ++n)
            acc[m][n] = (f32x4){0.f, 0.f, 0.f, 0.f};

    // prologue: stage tiles 0,1,2 (12 loads in flight), land tile 0
    STAGE_A(0 - 3 + 3); STAGE_B(0);
    STAGE_A(1);         STAGE_B(1);
    STAGE_A(2);         STAGE_B(2);
    asm volatile("s_waitcnt vmcnt(8)" ::: "memory");
    __builtin_amdgcn_s_barrier();

    #pragma unroll 4
    for (int t = 0; t < NTILES - 3; ++t)            // t = 0..71, stage t+3
        BODY(t, 1, "s_waitcnt vmcnt(8)");
    BODY(NTILES - 3, 0, "s_waitcnt vmcnt(4)");      // t = 72
    BODY(NTILES - 2, 0, "s_waitcnt vmcnt(0)");      // t = 73
    BODY(NTILES - 1, 0, "");                        // t = 74

    // epilogue: C/D layout col = lane&15, row = (lane>>4)*4 + reg  [m89]
    const int c_col0 = colBase + wn * 64 + (lane & 15);
    const size_t c_row0 = rowBase + wm * 128 + (lane >> 4) * 4;
    #pragma unroll
    for (int n = 0; n < 4; ++n) {
        const int gcol = c_col0 + n * 16;
        const float bv = bias[gcol];
        #pragma unroll
        for (int m = 0; m < 8; ++m) {
            const size_t grow = c_row0 + m * 16;
            #pragma unroll
            for (int r = 0; r < 4; ++r)
                C[(grow + r) * HP + gcol] = acc[m][n][r] + bv;
        }
    }
}

// ---------------------------------------------------------------------------
// Temporal phase: per batch row, all 25 steps, mem1/mem2 in registers.
// ---------------------------------------------------------------------------
__global__ __launch_bounds__(256)
void phase2_kernel(const float* __restrict__ cur1, const float* __restrict__ w2t,
                   const float* __restrict__ b2, float* __restrict__ out)
{
    __shared__ float w2s[HP * DOUT];   // 40 KB
    const int tid = threadIdx.x;
    for (int i = tid; i < HP * DOUT; i += 256) w2s[i] = w2t[i];

    const int lane = tid & 63;
    const int wave = tid >> 6;
    const int b = blockIdx.x * 4 + wave;

    float m1[16];
    #pragma unroll
    for (int i = 0; i < 16; ++i) m1[i] = 0.f;
    float m2[DOUT], b2r[DOUT];
    #pragma unroll
    for (int o = 0; o < DOUT; ++o) { m2[o] = 0.f; b2r[o] = b2[o]; }
    __syncthreads();

    for (int t = 0; t < T_STEPS; ++t) {
        const float* cr = cur1 + ((size_t)t * BATCH + b) * HP;
        float p[DOUT];
        #pragma unroll
        for (int o = 0; o < DOUT; ++o) p[o] = 0.f;

        #pragma unroll
        for (int c = 0; c < 4; ++c) {
            const float4 cu = *(const float4*)(cr + c * 256 + lane * 4);
            const float cv[4] = {cu.x, cu.y, cu.z, cu.w};
            #pragma unroll
            for (int j = 0; j < 4; ++j) {
                const float mo = m1[c * 4 + j];
                const float rs = (mo > 1.0f) ? 1.0f : 0.0f;
                const float mn = 0.95f * mo + cv[j] - rs;
                m1[c * 4 + j] = mn;
                if (mn > 1.0f) {
                    const float* wr = w2s + (c * 256 + lane * 4 + j) * DOUT;
                    #pragma unroll
                    for (int o = 0; o < DOUT; ++o) p[o] += wr[o];
                }
            }
        }
        #pragma unroll
        for (int o = 0; o < DOUT; ++o) {
            float v = p[o];
            #pragma unroll
            for (int msk = 32; msk > 0; msk >>= 1) v += __shfl_xor(v, msk, 64);
            p[o] = v;
        }
        #pragma unroll
        for (int o = 0; o < DOUT; ++o) {
            const float cur2 = p[o] + b2r[o];
            const float mo = m2[o];
            const float rs = (mo > 1.0f) ? 1.0f : 0.0f;
            m2[o] = 0.95f * mo + cur2 - rs;
        }
        if (lane < DOUT)
            out[(size_t)t * (BATCH * DOUT) + (size_t)b * DOUT + lane] =
                (m2[lane] > 1.0f) ? 1.0f : 0.0f;
    }
    if (lane < DOUT)
        out[(size_t)T_STEPS * BATCH * DOUT + (size_t)b * DOUT + lane] = m2[lane];
}

// ---------------------------------------------------------------------------
extern "C" void kernel_launch(void* const* d_in, const int* in_sizes, int n_in,
                              void* d_out, int out_size, void* d_ws, size_t ws_size,
                              hipStream_t stream)
{
    const float* x  = (const float*)d_in[0];
    const float* w1 = (const float*)d_in[1];
    const float* b1 = (const float*)d_in[2];
    const float* w2 = (const float*)d_in[3];
    const float* b2 = (const float*)d_in[4];
    float* out = (float*)d_out;

    char* wsb = (char*)d_ws;
    f16*   Ah   = (f16*)(wsb);                                   // 327,680,000 B
    f16*   Wh   = (f16*)(wsb + 327680000);                       //   4,915,200 B
    float* cur1 = (float*)(wsb + 327680000 + 4915200);           // 419,430,400 B
    float* b1p  = (float*)(wsb + 327680000 + 4915200 + 419430400);
    float* w2t  = (float*)(wsb + 327680000 + 4915200 + 419430400 + 4096);

    aconv_kernel<<<4096, 256, 0, stream>>>(x, Ah);
    wconv_kernel<<<1024, 256, 0, stream>>>(w1, b1, w2, Wh, b1p, w2t);
    gemm_kernel<<<1600, 512, 0, stream>>>(Ah, Wh, b1p, cur1);
    phase2_kernel<<<1024, 256, 0, stream>>>(cur1, w2t, b2, out);
}